// Round 1
// baseline (285.971 us; speedup 1.0000x reference)
//
#include <hip/hip_runtime.h>
#include <math.h>

#define B_    256
#define I_    1152
#define J_    10
#define DIN_  8
#define DOUT_ 16

// s_accum tiling: 16 batches x 36 i's per block, 256 threads = (16 b) x (16 d)
#define BB   16
#define NBC  (B_/BB)     // 16 batch chunks
#define IC   36
#define NIC  (I_/IC)     // 32 i chunks

// ---------------------------------------------------------------------------
// Phase A: s_acc[b,j,d] += sum_{i in chunk} softmax(b)[i,j] * (W[i,j,d,:].x[b,i,:])
// softmax over j computed inline from current logits.
// ---------------------------------------------------------------------------
__global__ __launch_bounds__(256)
void s_accum_kernel(const float* __restrict__ x, const float* __restrict__ W,
                    const float* __restrict__ blog, float* __restrict__ s_acc)
{
    const int tid = threadIdx.x;
    const int bc  = blockIdx.x & (NBC - 1);   // batch chunk
    const int ic  = blockIdx.x / NBC;         // i chunk
    const int i0  = ic * IC;
    const int b0  = bc * BB;
    const int b_local = tid >> 4;             // 0..15
    const int d       = tid & 15;             // 0..15

    __shared__ float x_lds[BB * IC * DIN_];   // 16*36*8 = 4608 f = 18 KB
    __shared__ float c_lds[IC * J_];          // 360 f

    // cooperative load of x[b0..b0+15, i0..i0+35, :] (contiguous 288 f per b-row)
    {
        const int f4_per_b = IC * DIN_ / 4;   // 72 float4 per batch row
        for (int idx = tid; idx < BB * f4_per_b; idx += 256) {
            int bl = idx / f4_per_b;
            int r  = idx - bl * f4_per_b;
            float4 v = ((const float4*)(x + (size_t)(b0 + bl) * I_ * DIN_
                                          + (size_t)i0 * DIN_))[r];
            ((float4*)x_lds)[bl * f4_per_b + r] = v;
        }
    }
    // inline softmax over j for this chunk's i rows (softmax(0)=uniform at iter 0)
    if (tid < IC) {
        const float* br = blog + (size_t)(i0 + tid) * J_;
        float bv[J_];
        float mx = -1e30f;
        #pragma unroll
        for (int j = 0; j < J_; ++j) { bv[j] = br[j]; mx = fmaxf(mx, bv[j]); }
        float sum = 0.f;
        #pragma unroll
        for (int j = 0; j < J_; ++j) { bv[j] = __expf(bv[j] - mx); sum += bv[j]; }
        float inv = 1.f / sum;
        #pragma unroll
        for (int j = 0; j < J_; ++j) c_lds[tid * J_ + j] = bv[j] * inv;
    }
    __syncthreads();

    float acc[J_];
    #pragma unroll
    for (int j = 0; j < J_; ++j) acc[j] = 0.f;

    for (int il = 0; il < IC; ++il) {
        const int i = i0 + il;
        float4 xa = ((const float4*)x_lds)[(b_local * IC + il) * 2 + 0];
        float4 xb = ((const float4*)x_lds)[(b_local * IC + il) * 2 + 1];
        // W row for this (i, j, d): 8 contiguous floats = 2 float4
        const float4* wp = (const float4*)(W + (size_t)i * J_ * DOUT_ * DIN_
                                             + (size_t)d * DIN_);
        #pragma unroll
        for (int j = 0; j < J_; ++j) {
            float4 w0 = wp[j * 32 + 0];       // j stride = DOUT*DIN = 128 f = 32 float4
            float4 w1 = wp[j * 32 + 1];
            float dot = w0.x * xa.x + w0.y * xa.y + w0.z * xa.z + w0.w * xa.w
                      + w1.x * xb.x + w1.y * xb.y + w1.z * xb.z + w1.w * xb.w;
            acc[j] = fmaf(c_lds[il * J_ + j], dot, acc[j]);
        }
    }

    float* sp = s_acc + (size_t)(b0 + b_local) * J_ * DOUT_ + d;
    #pragma unroll
    for (int j = 0; j < J_; ++j)
        atomicAdd(sp + j * DOUT_, acc[j]);
}

// ---------------------------------------------------------------------------
// squash: s = v * |v| / (1 + |v|^2) over d=16; writes s_out, re-zeros s_acc.
// 16-lane shfl reduction (d group lives in consecutive lanes).
// ---------------------------------------------------------------------------
__global__ __launch_bounds__(256)
void squash_kernel(float* __restrict__ s_acc, float* __restrict__ s_out)
{
    int gid = blockIdx.x * 256 + threadIdx.x;   // 40960 total
    float v  = s_acc[gid];
    float sq = v * v;
    #pragma unroll
    for (int off = 1; off < 16; off <<= 1)
        sq += __shfl_xor(sq, off, 16);
    float l2 = sqrtf(sq);
    s_out[gid] = v * (l2 / (1.f + sq));
    s_acc[gid] = 0.f;                            // ready for next iteration
}

// ---------------------------------------------------------------------------
// Phase B: blog[i,j] += sum_{b,d} (W[i,j,d,:].x[b,i,:]) * s[b,j,d]
// One block per i; thread = one batch. W addresses thread-uniform -> s_loads.
// ---------------------------------------------------------------------------
__global__ __launch_bounds__(256)
void b_update_kernel(const float* __restrict__ x, const float* __restrict__ W,
                     const float* __restrict__ s, float* __restrict__ blog)
{
    const int i    = blockIdx.x;
    const int tb   = threadIdx.x;   // batch index
    const int lane = tb & 63;
    const int wid  = tb >> 6;

    const float4* xp = (const float4*)(x + ((size_t)tb * I_ + i) * DIN_);
    float4 xa = xp[0];
    float4 xb = xp[1];

    __shared__ float wred[J_][4];

    const float* wbase = W + (size_t)i * J_ * DOUT_ * DIN_;
    const float* srow  = s + (size_t)tb * J_ * DOUT_;

    #pragma unroll
    for (int j = 0; j < J_; ++j) {
        float accj = 0.f;
        const float* wj = wbase + j * DOUT_ * DIN_;
        const float* sj = srow + j * DOUT_;
        #pragma unroll
        for (int d = 0; d < DOUT_; ++d) {
            const float* wr = wj + d * DIN_;    // uniform -> scalar loads
            float dot = wr[0] * xa.x + wr[1] * xa.y + wr[2] * xa.z + wr[3] * xa.w
                      + wr[4] * xb.x + wr[5] * xb.y + wr[6] * xb.z + wr[7] * xb.w;
            accj = fmaf(dot, sj[d], accj);
        }
        #pragma unroll
        for (int off = 32; off >= 1; off >>= 1)
            accj += __shfl_xor(accj, off, 64);
        if (lane == 0) wred[j][wid] = accj;
    }
    __syncthreads();
    if (tb < J_) {
        float v = wred[tb][0] + wred[tb][1] + wred[tb][2] + wred[tb][3];
        blog[(size_t)i * J_ + tb] += v;
    }
}

// ---------------------------------------------------------------------------
extern "C" void kernel_launch(void* const* d_in, const int* in_sizes, int n_in,
                              void* d_out, int out_size, void* d_ws, size_t ws_size,
                              hipStream_t stream)
{
    const float* x = (const float*)d_in[0];   // [B, I, DIN]
    const float* W = (const float*)d_in[1];   // [I, J, DOUT, DIN]
    float* s_out = (float*)d_out;             // [B, J, DOUT] — also intermediate s
    float* s_acc = (float*)d_ws;              // 40960 f
    float* blog  = s_acc + B_ * J_ * DOUT_;   // 11520 f (routing logits)

    // zero s_acc + logits (ws is poisoned 0xAA before every launch)
    hipMemsetAsync(d_ws, 0, (size_t)(B_ * J_ * DOUT_ + I_ * J_) * sizeof(float),
                   stream);

    for (int it = 0; it < 3; ++it) {
        s_accum_kernel<<<NBC * NIC, 256, 0, stream>>>(x, W, blog, s_acc);
        squash_kernel<<<(B_ * J_ * DOUT_) / 256, 256, 0, stream>>>(s_acc, s_out);
        if (it < 2)
            b_update_kernel<<<I_, 256, 0, stream>>>(x, W, s_out, blog);
    }
}

// Round 2
// 263.283 us; speedup vs baseline: 1.0862x; 1.0862x over previous
//
#include <hip/hip_runtime.h>
#include <math.h>

#define B_    256
#define I_    1152
#define J_    10
#define DIN_  8
#define DOUT_ 16

// s_accum tiling: 16 batches x 36 i's x 5 j's per block; 256 threads = 16b x 16d
#define BB   16
#define NBC  (B_/BB)     // 16 batch chunks
#define IC   36
#define NIC  (I_/IC)     // 32 i chunks
#define JG   5           // j's per block
#define NJG  (J_/JG)     // 2 j groups

// ---------------------------------------------------------------------------
// Phase A: s_acc[b,j,d] += sum_{i in chunk} softmax(b)[i,j] * (W[i,j,d,:].x[b,i,:])
// Grid = NBC * NIC * NJG = 1024 blocks (4/CU, 16 waves/CU).
// ---------------------------------------------------------------------------
__global__ __launch_bounds__(256)
void s_accum_kernel(const float* __restrict__ x, const float* __restrict__ W,
                    const float* __restrict__ blog, float* __restrict__ s_acc)
{
    const int tid = threadIdx.x;
    const int bc  = blockIdx.x & (NBC - 1);          // bits 0..3
    const int ic  = (blockIdx.x >> 4) & (NIC - 1);   // bits 4..8
    const int jg  = blockIdx.x >> 9;                 // bit 9
    const int j0  = jg * JG;
    const int i0  = ic * IC;
    const int b0  = bc * BB;
    const int b_local = tid >> 4;             // 0..15
    const int d       = tid & 15;             // 0..15

    __shared__ float x_lds[BB * IC * DIN_];   // 18 KB
    __shared__ float c_lds[IC * JG];          // 180 f

    // cooperative load of x[b0..b0+15, i0..i0+35, :]
    {
        const int f4_per_b = IC * DIN_ / 4;   // 72 float4 per batch row
        for (int idx = tid; idx < BB * f4_per_b; idx += 256) {
            int bl = idx / f4_per_b;
            int r  = idx - bl * f4_per_b;
            ((float4*)x_lds)[idx] =
                ((const float4*)(x + (size_t)(b0 + bl) * I_ * DIN_
                                   + (size_t)i0 * DIN_))[r];
        }
    }
    // inline softmax over all 10 j (store only our 5)
    if (tid < IC) {
        const float* br = blog + (size_t)(i0 + tid) * J_;
        float bv[J_];
        float mx = -1e30f;
        #pragma unroll
        for (int j = 0; j < J_; ++j) { bv[j] = br[j]; mx = fmaxf(mx, bv[j]); }
        float sum = 0.f;
        #pragma unroll
        for (int j = 0; j < J_; ++j) { bv[j] = __expf(bv[j] - mx); sum += bv[j]; }
        float inv = 1.f / sum;
        #pragma unroll
        for (int jj = 0; jj < JG; ++jj) c_lds[tid * JG + jj] = bv[j0 + jj] * inv;
    }
    __syncthreads();

    float acc[JG];
    #pragma unroll
    for (int jj = 0; jj < JG; ++jj) acc[jj] = 0.f;

    #pragma unroll 2
    for (int il = 0; il < IC; ++il) {
        const int i = i0 + il;
        float4 xa = ((const float4*)x_lds)[(b_local * IC + il) * 2 + 0];
        float4 xb = ((const float4*)x_lds)[(b_local * IC + il) * 2 + 1];
        // W[i, j0+jj, d, :]: 8 contiguous floats = 2 float4; j stride = 32 float4
        const float4* wp = (const float4*)(W + (size_t)i * J_ * DOUT_ * DIN_
                                             + (size_t)j0 * DOUT_ * DIN_
                                             + (size_t)d * DIN_);
        #pragma unroll
        for (int jj = 0; jj < JG; ++jj) {
            float4 w0 = wp[jj * 32 + 0];
            float4 w1 = wp[jj * 32 + 1];
            float dot = w0.x * xa.x + w0.y * xa.y + w0.z * xa.z + w0.w * xa.w
                      + w1.x * xb.x + w1.y * xb.y + w1.z * xb.z + w1.w * xb.w;
            acc[jj] = fmaf(c_lds[il * JG + jj], dot, acc[jj]);
        }
    }

    float* sp = s_acc + (size_t)(b0 + b_local) * J_ * DOUT_ + (size_t)j0 * DOUT_ + d;
    #pragma unroll
    for (int jj = 0; jj < JG; ++jj)
        atomicAdd(sp + jj * DOUT_, acc[jj]);
}

// ---------------------------------------------------------------------------
// squash: s = v*|v|/(1+|v|^2); writes s_out [b,j,d] AND transposed s_t [j,b,d];
// re-zeros s_acc for the next routing iteration.
// ---------------------------------------------------------------------------
__global__ __launch_bounds__(256)
void squash_kernel(float* __restrict__ s_acc, float* __restrict__ s_out,
                   float* __restrict__ s_t)
{
    int gid = blockIdx.x * 256 + threadIdx.x;   // 40960
    float v  = s_acc[gid];
    float sq = v * v;
    #pragma unroll
    for (int off = 1; off < 16; off <<= 1)
        sq += __shfl_xor(sq, off, 16);
    float l2 = sqrtf(sq);
    float val = v * (l2 / (1.f + sq));
    s_out[gid] = val;
    int b  = gid / (J_ * DOUT_);
    int jd = gid - b * (J_ * DOUT_);
    int j  = jd >> 4;
    int dd = jd & 15;
    s_t[((size_t)j * B_ + b) * DOUT_ + dd] = val;
    s_acc[gid] = 0.f;
}

// ---------------------------------------------------------------------------
// Phase B: blog[i,j] += sum_{b,d} (W[i,j,d,:].x[b,i,:]) * s[b,j,d]
// One block per i; thread = batch. s read from transposed s_t (coalesced
// 4xfloat4 per (j,thread)); W reads are wave-uniform -> scalar loads.
// ---------------------------------------------------------------------------
__global__ __launch_bounds__(256)
void b_update_kernel(const float* __restrict__ x, const float* __restrict__ W,
                     const float* __restrict__ s_t, float* __restrict__ blog)
{
    const int i    = blockIdx.x;
    const int tb   = threadIdx.x;   // batch index
    const int lane = tb & 63;
    const int wid  = tb >> 6;

    const float4* xp = (const float4*)(x + ((size_t)tb * I_ + i) * DIN_);
    float4 xa = xp[0];
    float4 xb = xp[1];

    __shared__ float wred[J_][4];

    const float* wbase = W + (size_t)i * J_ * DOUT_ * DIN_;

    #pragma unroll
    for (int j = 0; j < J_; ++j) {
        const float4* sp = (const float4*)(s_t + ((size_t)j * B_ + tb) * DOUT_);
        float4 s0 = sp[0], s1 = sp[1], s2 = sp[2], s3 = sp[3];
        const float sv[DOUT_] = {s0.x, s0.y, s0.z, s0.w,
                                 s1.x, s1.y, s1.z, s1.w,
                                 s2.x, s2.y, s2.z, s2.w,
                                 s3.x, s3.y, s3.z, s3.w};
        float accj = 0.f;
        const float* wj = wbase + j * DOUT_ * DIN_;
        #pragma unroll
        for (int d = 0; d < DOUT_; ++d) {
            const float* wr = wj + d * DIN_;    // uniform -> scalar loads
            float dot = wr[0] * xa.x + wr[1] * xa.y + wr[2] * xa.z + wr[3] * xa.w
                      + wr[4] * xb.x + wr[5] * xb.y + wr[6] * xb.z + wr[7] * xb.w;
            accj = fmaf(dot, sv[d], accj);
        }
        #pragma unroll
        for (int off = 32; off >= 1; off >>= 1)
            accj += __shfl_xor(accj, off, 64);
        if (lane == 0) wred[j][wid] = accj;
    }
    __syncthreads();
    if (tb < J_) {
        float v = wred[tb][0] + wred[tb][1] + wred[tb][2] + wred[tb][3];
        blog[(size_t)i * J_ + tb] += v;
    }
}

// ---------------------------------------------------------------------------
extern "C" void kernel_launch(void* const* d_in, const int* in_sizes, int n_in,
                              void* d_out, int out_size, void* d_ws, size_t ws_size,
                              hipStream_t stream)
{
    const float* x = (const float*)d_in[0];   // [B, I, DIN]
    const float* W = (const float*)d_in[1];   // [I, J, DOUT, DIN]
    float* s_out = (float*)d_out;             // [B, J, DOUT]
    float* s_acc = (float*)d_ws;                         // 40960 f
    float* blog  = s_acc + B_ * J_ * DOUT_;              // 11520 f
    float* s_t   = blog + I_ * J_;                       // 40960 f (transposed s)

    // zero s_acc + logits
    hipMemsetAsync(d_ws, 0, (size_t)(B_ * J_ * DOUT_ + I_ * J_) * sizeof(float),
                   stream);

    for (int it = 0; it < 3; ++it) {
        s_accum_kernel<<<NBC * NIC * NJG, 256, 0, stream>>>(x, W, blog, s_acc);
        squash_kernel<<<(B_ * J_ * DOUT_) / 256, 256, 0, stream>>>(s_acc, s_out, s_t);
        if (it < 2)
            b_update_kernel<<<I_, 256, 0, stream>>>(x, W, s_t, blog);
    }
}

// Round 3
// 221.479 us; speedup vs baseline: 1.2912x; 1.1888x over previous
//
#include <hip/hip_runtime.h>
#include <math.h>

#define B_    256
#define I_    1152
#define J_    10
#define DIN_  8
#define DOUT_ 16

// s_accum tiling: 16 batches x 16 i's x 5 j's per block; 256 threads = 16b x 16d
#define BB   16
#define NBC  (B_/BB)     // 16 batch chunks
#define IC   16
#define NIC  (I_/IC)     // 72 i chunks
#define JG   5
#define NJG  (J_/JG)     // 2 j groups
// grid = NBC*NIC*NJG = 2304 blocks; LDS 48.4 KB -> 3 blocks/CU

// ---------------------------------------------------------------------------
// Phase A: s_acc[b,j,d] += sum_i softmax(b)[i,j] * (W[i,j,d,:].x[b,i,:])
// W tile staged in LDS (d-innermost float4 layout, conflict-free), pre-scaled
// by the coupling coefficient c so the inner loop is pure dot products.
// ---------------------------------------------------------------------------
__global__ __launch_bounds__(256)
void s_accum_kernel(const float* __restrict__ x, const float* __restrict__ W,
                    const float* __restrict__ blog, float* __restrict__ s_acc)
{
    const int tid = threadIdx.x;
    const int bc  = blockIdx.x & (NBC - 1);
    const int t   = blockIdx.x >> 4;
    const int jg  = t / NIC;
    const int ic  = t - jg * NIC;
    const int j0  = jg * JG;
    const int i0  = ic * IC;
    const int b0  = bc * BB;
    const int b_local = tid >> 4;             // 0..15
    const int d       = tid & 15;             // 0..15

    __shared__ float4 w_lds[IC * JG * 32];    // 2560 f4 = 40 KB, [(row)*2+k4][d]
    __shared__ float4 x_lds[BB * IC * 2];     // 512 f4 = 8 KB
    __shared__ float  c_lds[IC * JG];         // 80 f

    // --- stage W tile (raw). global f4 idx within (il,jj) row == d*2+k4 == r2
    const float4* Wg = (const float4*)W;
    #pragma unroll
    for (int idx = tid; idx < IC * JG * 32; idx += 256) {
        int row = idx >> 5;                   // il*JG + jj
        int r2  = idx & 31;                   // d*2 + k4
        int il  = row / JG;
        int jj  = row - il * JG;
        int dd  = r2 >> 1;
        int k4  = r2 & 1;
        float4 v = Wg[(size_t)(i0 + il) * (J_ * 32) + (size_t)(j0 + jj) * 32 + r2];
        w_lds[(row * 2 + k4) * 16 + dd] = v;  // d-innermost
    }
    // --- stage x tile
    {
        const int f4_per_b = IC * DIN_ / 4;   // 32
        #pragma unroll
        for (int idx = tid; idx < BB * f4_per_b; idx += 256) {
            int bl = idx / f4_per_b;
            int r  = idx - bl * f4_per_b;
            x_lds[idx] = ((const float4*)(x + (size_t)(b0 + bl) * I_ * DIN_
                                            + (size_t)i0 * DIN_))[r];
        }
    }
    // --- softmax over all 10 j; keep our 5
    if (tid < IC) {
        const float* br = blog + (size_t)(i0 + tid) * J_;
        float bv[J_];
        float mx = -1e30f;
        #pragma unroll
        for (int j = 0; j < J_; ++j) { bv[j] = br[j]; mx = fmaxf(mx, bv[j]); }
        float sum = 0.f;
        #pragma unroll
        for (int j = 0; j < J_; ++j) { bv[j] = __expf(bv[j] - mx); sum += bv[j]; }
        float inv = 1.f / sum;
        #pragma unroll
        for (int jj = 0; jj < JG; ++jj) c_lds[tid * JG + jj] = bv[j0 + jj] * inv;
    }
    __syncthreads();

    // --- scale staged W by c (linear idx: row == idx>>5 in both layouts)
    #pragma unroll
    for (int idx = tid; idx < IC * JG * 32; idx += 256) {
        float c = c_lds[idx >> 5];
        float4 v = w_lds[idx];
        v.x *= c; v.y *= c; v.z *= c; v.w *= c;
        w_lds[idx] = v;
    }
    __syncthreads();

    float acc[JG];
    #pragma unroll
    for (int jj = 0; jj < JG; ++jj) acc[jj] = 0.f;

    for (int il = 0; il < IC; ++il) {
        float4 xa = x_lds[(b_local * IC + il) * 2 + 0];   // broadcast across d
        float4 xb = x_lds[(b_local * IC + il) * 2 + 1];
        const float4* wrow = &w_lds[il * JG * 32];
        #pragma unroll
        for (int jj = 0; jj < JG; ++jj) {
            float4 w0 = wrow[jj * 32 + d];        // 16 contiguous f4 across lanes
            float4 w1 = wrow[jj * 32 + 16 + d];
            acc[jj] += w0.x * xa.x + w0.y * xa.y + w0.z * xa.z + w0.w * xa.w
                     + w1.x * xb.x + w1.y * xb.y + w1.z * xb.z + w1.w * xb.w;
        }
    }

    float* sp = s_acc + (size_t)(b0 + b_local) * J_ * DOUT_ + (size_t)j0 * DOUT_ + d;
    #pragma unroll
    for (int jj = 0; jj < JG; ++jj)
        atomicAdd(sp + jj * DOUT_, acc[jj]);
}

// ---------------------------------------------------------------------------
// squash: s = v*|v|/(1+|v|^2); writes s_out [b,j,d] and transposed s_t [j,b,d];
// re-zeros s_acc.
// ---------------------------------------------------------------------------
__global__ __launch_bounds__(256)
void squash_kernel(float* __restrict__ s_acc, float* __restrict__ s_out,
                   float* __restrict__ s_t)
{
    int gid = blockIdx.x * 256 + threadIdx.x;   // 40960
    float v  = s_acc[gid];
    float sq = v * v;
    #pragma unroll
    for (int off = 1; off < 16; off <<= 1)
        sq += __shfl_xor(sq, off, 16);
    float l2 = sqrtf(sq);
    float val = v * (l2 / (1.f + sq));
    s_out[gid] = val;
    int b  = gid / (J_ * DOUT_);
    int jd = gid - b * (J_ * DOUT_);
    int j  = jd >> 4;
    int dd = jd & 15;
    s_t[((size_t)j * B_ + b) * DOUT_ + dd] = val;
    s_acc[gid] = 0.f;
}

// ---------------------------------------------------------------------------
// Phase B: blog[i,j] += sum_{b,d} (W[i,j,d,:].x[b,i,:]) * s[b,j,d]
// One block per i; thread = batch. W[i] row (5 KB) staged in LDS; inner reads
// are same-address broadcasts (conflict-free).
// ---------------------------------------------------------------------------
__global__ __launch_bounds__(256)
void b_update_kernel(const float* __restrict__ x, const float* __restrict__ W,
                     const float* __restrict__ s_t, float* __restrict__ blog)
{
    const int i    = blockIdx.x;
    const int tb   = threadIdx.x;   // batch index
    const int lane = tb & 63;
    const int wid  = tb >> 6;

    __shared__ float4 w_lds[J_ * DOUT_ * 2];   // 320 f4 = 5 KB, [j][d][k4]
    __shared__ float wred[J_][4];

    const float4* Wg = (const float4*)W + (size_t)i * (J_ * DOUT_ * 2);
    #pragma unroll
    for (int idx = tb; idx < J_ * DOUT_ * 2; idx += 256)
        w_lds[idx] = Wg[idx];

    const float4* xp = (const float4*)(x + ((size_t)tb * I_ + i) * DIN_);
    float4 xa = xp[0];
    float4 xb = xp[1];
    __syncthreads();

    #pragma unroll
    for (int j = 0; j < J_; ++j) {
        const float4* sp = (const float4*)(s_t + ((size_t)j * B_ + tb) * DOUT_);
        float4 s0 = sp[0], s1 = sp[1], s2 = sp[2], s3 = sp[3];
        const float sv[DOUT_] = {s0.x, s0.y, s0.z, s0.w,
                                 s1.x, s1.y, s1.z, s1.w,
                                 s2.x, s2.y, s2.z, s2.w,
                                 s3.x, s3.y, s3.z, s3.w};
        float accj = 0.f;
        #pragma unroll
        for (int d = 0; d < DOUT_; ++d) {
            float4 w0 = w_lds[(j * DOUT_ + d) * 2 + 0];   // broadcast
            float4 w1 = w_lds[(j * DOUT_ + d) * 2 + 1];
            float dot = w0.x * xa.x + w0.y * xa.y + w0.z * xa.z + w0.w * xa.w
                      + w1.x * xb.x + w1.y * xb.y + w1.z * xb.z + w1.w * xb.w;
            accj = fmaf(dot, sv[d], accj);
        }
        #pragma unroll
        for (int off = 32; off >= 1; off >>= 1)
            accj += __shfl_xor(accj, off, 64);
        if (lane == 0) wred[j][wid] = accj;
    }
    __syncthreads();
    if (tb < J_) {
        float v = wred[tb][0] + wred[tb][1] + wred[tb][2] + wred[tb][3];
        blog[(size_t)i * J_ + tb] += v;
    }
}

// ---------------------------------------------------------------------------
extern "C" void kernel_launch(void* const* d_in, const int* in_sizes, int n_in,
                              void* d_out, int out_size, void* d_ws, size_t ws_size,
                              hipStream_t stream)
{
    const float* x = (const float*)d_in[0];   // [B, I, DIN]
    const float* W = (const float*)d_in[1];   // [I, J, DOUT, DIN]
    float* s_out = (float*)d_out;             // [B, J, DOUT]
    float* s_acc = (float*)d_ws;                         // 40960 f
    float* blog  = s_acc + B_ * J_ * DOUT_;              // 11520 f
    float* s_t   = blog + I_ * J_;                       // 40960 f (transposed s)

    hipMemsetAsync(d_ws, 0, (size_t)(B_ * J_ * DOUT_ + I_ * J_) * sizeof(float),
                   stream);

    for (int it = 0; it < 3; ++it) {
        s_accum_kernel<<<NBC * NIC * NJG, 256, 0, stream>>>(x, W, blog, s_acc);
        squash_kernel<<<(B_ * J_ * DOUT_) / 256, 256, 0, stream>>>(s_acc, s_out, s_t);
        if (it < 2)
            b_update_kernel<<<I_, 256, 0, stream>>>(x, W, s_t, blog);
    }
}